// Round 2
// baseline (650.277 us; speedup 1.0000x reference)
//
#include <hip/hip_runtime.h>
#include <hip/hip_bf16.h>

// Channel attention (4 heads, dilated 3x3 key convs d=1,2,4,8), f16 MFMA pipeline.
// (f16 not bf16: 4x lower rounding noise; score-sum over N=16384 needs it.)
//
// ws layout (bytes):
//   kbuf : [0,           67108864)   k  f16 [h][b][p][n]
//   vT   : [67108864,   134217728)   v  f16 [h][b][n][p]   (pixel-major)
//   attn : [134217728,  134479872)   attn f16 [h][b][o][p]
//   Wqv  : [134479872,  134742016)   f16 (512x256)
//   Wkb  : [134742016,  135921664)   f16 (4,9,64,256)
// d_out reused as scratch (dead before final kernel):
//   xT   : bytes [0, 64Mi)   f16 [b][n][c]
//   q    : bytes [64Mi,128Mi) f16 [h][b][o][n]
//   part : bytes [0, 4Mi)    fp32 partial scores (written AFTER conv, xT dead)

typedef __attribute__((ext_vector_type(8))) _Float16 f16x8;
typedef __attribute__((ext_vector_type(4))) float f32x4;

__device__ __forceinline__ unsigned short f2h(float f) {
  union { _Float16 h; unsigned short u; } v;
  v.h = (_Float16)f;
  return v.u;
}

__device__ __forceinline__ f32x4 mfma16(f16x8 a, f16x8 b, f32x4 c) {
  return __builtin_amdgcn_mfma_f32_16x16x32_f16(a, b, c, 0, 0, 0);
}

// swizzled index into a [R][64]-ushort tile (128B rows): XOR bits 4..6 of byte off
__device__ __forceinline__ int sw(int row, int c) {
  return row * 64 + ((((c << 1) ^ ((row & 7) << 4)) >> 1));
}

// ---------------- weight prep ----------------
__global__ __launch_bounds__(256) void prep(const float* __restrict__ Wq,
                                            const float* __restrict__ Wv,
                                            const float* __restrict__ Wk,
                                            unsigned short* __restrict__ Wqv,
                                            unsigned short* __restrict__ Wkb) {
  int i = blockIdx.x * 256 + threadIdx.x;
  const int total = 131072 + 589824;
  if (i >= total) return;
  if (i < 131072) {
    Wqv[i] = f2h(i < 65536 ? Wq[i] : Wv[i - 65536]);
  } else {
    int j = i - 131072;               // ((h*9+t)*64+p)*256 + c
    int c = j & 255; int r = j >> 8; int p = r & 63; int ht = r >> 6;
    int t = ht % 9; int h = ht / 9;
    Wkb[j] = f2h(Wk[(size_t)(h * 64 + p) * 2304 + c * 9 + t]);
  }
}

// ---------------- x (b,c,n) fp32 -> xT (b,n,c) f16 ----------------
__global__ __launch_bounds__(256) void xpose(const float* __restrict__ x,
                                             unsigned short* __restrict__ xT) {
  __shared__ unsigned short tile[64][66];
  int n0 = blockIdx.x * 64, c0 = blockIdx.y * 64, b = blockIdx.z;
  int t = threadIdx.x;
  int r = t >> 2, q = t & 3;
  const float* src = x + (size_t)b * 4194304 + (size_t)(c0 + r) * 16384 + n0 + q * 16;
#pragma unroll
  for (int i = 0; i < 4; i++) {
    float4 v = *(const float4*)(src + i * 4);
    tile[r][q * 16 + i * 4 + 0] = f2h(v.x);
    tile[r][q * 16 + i * 4 + 1] = f2h(v.y);
    tile[r][q * 16 + i * 4 + 2] = f2h(v.z);
    tile[r][q * 16 + i * 4 + 3] = f2h(v.w);
  }
  __syncthreads();
  int c = t & 63, pq = t >> 6;
  unsigned short* dst = xT + (size_t)b * 4194304 + (size_t)n0 * 256 + c0 + c;
#pragma unroll
  for (int i = 0; i < 16; i++) {
    int px = i * 4 + pq;
    dst[(size_t)px * 256] = tile[c][px];
  }
}

// ---------------- Q/V projection: C(64x256) = Wqv-tile @ xT-tile ----------------
__global__ __launch_bounds__(256) void proj(const unsigned short* __restrict__ xT,
                                            const unsigned short* __restrict__ Wqv,
                                            const float* __restrict__ bq,
                                            const float* __restrict__ bv,
                                            unsigned short* __restrict__ qout,
                                            unsigned short* __restrict__ vT) {
  __shared__ __align__(16) unsigned short As[64 * 64];
  __shared__ __align__(16) unsigned short Bs[256 * 64];
  int n0 = blockIdx.x * 256, m0 = blockIdx.y * 64, b = blockIdx.z;
  int tid = threadIdx.x, lane = tid & 63, w = tid >> 6;
  int l15 = lane & 15, uq = lane >> 4;
  const f32x4 fz = {0.f, 0.f, 0.f, 0.f};
  f32x4 acc[4][4];
#pragma unroll
  for (int i = 0; i < 4; i++)
#pragma unroll
    for (int j = 0; j < 4; j++) acc[i][j] = fz;

  const unsigned short* xb = xT + (size_t)b * 4194304;
  for (int k0 = 0; k0 < 256; k0 += 64) {
    __syncthreads();
    for (int p = tid; p < 512; p += 256) {
      int row = p >> 3, j = p & 7;
      uint4 v = *(const uint4*)(Wqv + (size_t)(m0 + row) * 256 + k0 + j * 8);
      *(uint4*)&As[sw(row, j * 8)] = v;
    }
    for (int p = tid; p < 2048; p += 256) {
      int px = p >> 3, j = p & 7;
      uint4 v = *(const uint4*)(xb + (size_t)(n0 + px) * 256 + k0 + j * 8);
      *(uint4*)&Bs[sw(px, j * 8)] = v;
    }
    __syncthreads();
#pragma unroll
    for (int kk = 0; kk < 2; kk++) {
      f16x8 bfr[4];
#pragma unroll
      for (int nf = 0; nf < 4; nf++)
        bfr[nf] = *(const f16x8*)&Bs[sw(w * 64 + nf * 16 + l15, kk * 32 + uq * 8)];
#pragma unroll
      for (int mf = 0; mf < 4; mf++) {
        f16x8 afr = *(const f16x8*)&As[sw(mf * 16 + l15, kk * 32 + uq * 8)];
#pragma unroll
        for (int nf = 0; nf < 4; nf++) acc[mf][nf] = mfma16(afr, bfr[nf], acc[mf][nf]);
      }
    }
  }
  if (m0 < 256) {
    int h = m0 >> 6;
    unsigned short* qb = qout + (size_t)((h * 8 + b) * 64) * 16384;
#pragma unroll
    for (int mf = 0; mf < 4; mf++)
#pragma unroll
      for (int nf = 0; nf < 4; nf++) {
        int n = n0 + w * 64 + nf * 16 + l15;
#pragma unroll
        for (int r = 0; r < 4; r++) {
          int m = m0 + mf * 16 + 4 * uq + r;
          qb[(size_t)(m & 63) * 16384 + n] = f2h(acc[mf][nf][r] + bq[m]);
        }
      }
  } else {
    int m0v = m0 - 256, h = m0v >> 6;
    unsigned short* vb = vT + (size_t)(h * 8 + b) * 16384 * 64;
#pragma unroll
    for (int mf = 0; mf < 4; mf++) {
      int p0 = mf * 16 + 4 * uq;
#pragma unroll
      for (int nf = 0; nf < 4; nf++) {
        int n = n0 + w * 64 + nf * 16 + l15;
        unsigned short t0 = f2h(acc[mf][nf][0] + bv[m0v + p0 + 0]);
        unsigned short t1 = f2h(acc[mf][nf][1] + bv[m0v + p0 + 1]);
        unsigned short t2 = f2h(acc[mf][nf][2] + bv[m0v + p0 + 2]);
        unsigned short t3 = f2h(acc[mf][nf][3] + bv[m0v + p0 + 3]);
        uint2 pk;
        pk.x = (unsigned)t0 | ((unsigned)t1 << 16);
        pk.y = (unsigned)t2 | ((unsigned)t3 << 16);
        *(uint2*)&vb[(size_t)n * 64 + p0] = pk;
      }
    }
  }
}

// ---------------- dilated 3x3 conv (keys): one output row per block ----------------
__global__ __launch_bounds__(256) void convk(const unsigned short* __restrict__ xT,
                                             const unsigned short* __restrict__ Wkb,
                                             const float* __restrict__ bk,
                                             unsigned short* __restrict__ kout) {
  __shared__ __align__(16) unsigned short As[64 * 64];
  __shared__ __align__(16) unsigned short Bs[3 * 144 * 64];
  int y = blockIdx.x, b = blockIdx.y, h = blockIdx.z;
  int d = 1 << h;
  int tid = threadIdx.x, lane = tid & 63, w = tid >> 6;
  int l15 = lane & 15, uq = lane >> 4;
  const unsigned short* xb = xT + (size_t)b * 4194304;
  const f32x4 fz = {0.f, 0.f, 0.f, 0.f};
  f32x4 acc[4][2];
#pragma unroll
  for (int i = 0; i < 4; i++) { acc[i][0] = fz; acc[i][1] = fz; }

  for (int k0 = 0; k0 < 256; k0 += 64) {
    __syncthreads();
    // stage halo union: 3 source rows x 144 px x 64 ch (zero-padded)
    for (int p = tid; p < 3456; p += 256) {
      int plane = p / 1152, rem = p - plane * 1152;
      int px = rem >> 3, j = rem & 7;
      int rrow = y + d * (plane - 1);
      int xc = px - d;
      uint4 v = {0u, 0u, 0u, 0u};
      if (rrow >= 0 && rrow < 128 && xc >= 0 && xc < 128)
        v = *(const uint4*)(xb + (size_t)(rrow * 128 + xc) * 256 + k0 + j * 8);
      *(uint4*)&Bs[plane * 9216 + sw(px, j * 8)] = v;
    }
    for (int t = 0; t < 9; t++) {
      if (t > 0) __syncthreads();
      for (int p = tid; p < 512; p += 256) {
        int row = p >> 3, j = p & 7;
        uint4 v = *(const uint4*)(Wkb + (size_t)((h * 9 + t) * 64 + row) * 256 + k0 + j * 8);
        *(uint4*)&As[sw(row, j * 8)] = v;
      }
      __syncthreads();
      int ty = t / 3, tx = t - ty * 3;
      int ub = w * 32 + d * tx + l15;  // halo slot u = x + d*tx
#pragma unroll
      for (int kk = 0; kk < 2; kk++) {
        f16x8 bfr0 = *(const f16x8*)&Bs[ty * 9216 + sw(ub, kk * 32 + uq * 8)];
        f16x8 bfr1 = *(const f16x8*)&Bs[ty * 9216 + sw(ub + 16, kk * 32 + uq * 8)];
#pragma unroll
        for (int mf = 0; mf < 4; mf++) {
          f16x8 afr = *(const f16x8*)&As[sw(mf * 16 + l15, kk * 32 + uq * 8)];
          acc[mf][0] = mfma16(afr, bfr0, acc[mf][0]);
          acc[mf][1] = mfma16(afr, bfr1, acc[mf][1]);
        }
      }
    }
  }
  unsigned short* kb = kout + (size_t)((h * 8 + b) * 64) * 16384;
#pragma unroll
  for (int mf = 0; mf < 4; mf++)
#pragma unroll
    for (int nf = 0; nf < 2; nf++) {
      int xcol = w * 32 + nf * 16 + l15;
      int n = y * 128 + xcol;
#pragma unroll
      for (int r = 0; r < 4; r++) {
        int p = mf * 16 + 4 * uq + r;
        kb[(size_t)p * 16384 + n] = f2h(acc[mf][nf][r] + bk[h * 64 + p]);
      }
    }
}

// ---------------- scores partials: q . k^T over n-chunk of 2048 ----------------
__global__ __launch_bounds__(256) void scoresk(const unsigned short* __restrict__ qin,
                                               const unsigned short* __restrict__ kin,
                                               float* __restrict__ part) {
  __shared__ __align__(16) unsigned short As[64 * 64];
  __shared__ __align__(16) unsigned short Bs[64 * 64];
  int nch = blockIdx.x, b = blockIdx.y, h = blockIdx.z;
  int tid = threadIdx.x, lane = tid & 63, w = tid >> 6;
  int l15 = lane & 15, uq = lane >> 4;
  const unsigned short* qb = qin + (size_t)((h * 8 + b) * 64) * 16384;
  const unsigned short* kb = kin + (size_t)((h * 8 + b) * 64) * 16384;
  int moff = (w >> 1) * 32, noff = (w & 1) * 32;
  const f32x4 fz = {0.f, 0.f, 0.f, 0.f};
  f32x4 acc[2][2] = {{fz, fz}, {fz, fz}};
  for (int ci = 0; ci < 32; ci++) {
    int nb = nch * 2048 + ci * 64;
    __syncthreads();
    for (int p = tid; p < 512; p += 256) {
      int row = p >> 3, j = p & 7;
      *(uint4*)&As[sw(row, j * 8)] = *(const uint4*)(qb + (size_t)row * 16384 + nb + j * 8);
      *(uint4*)&Bs[sw(row, j * 8)] = *(const uint4*)(kb + (size_t)row * 16384 + nb + j * 8);
    }
    __syncthreads();
#pragma unroll
    for (int kk = 0; kk < 2; kk++) {
      f16x8 b0 = *(const f16x8*)&Bs[sw(noff + l15, kk * 32 + uq * 8)];
      f16x8 b1 = *(const f16x8*)&Bs[sw(noff + 16 + l15, kk * 32 + uq * 8)];
      f16x8 a0 = *(const f16x8*)&As[sw(moff + l15, kk * 32 + uq * 8)];
      f16x8 a1 = *(const f16x8*)&As[sw(moff + 16 + l15, kk * 32 + uq * 8)];
      acc[0][0] = mfma16(a0, b0, acc[0][0]);
      acc[0][1] = mfma16(a0, b1, acc[0][1]);
      acc[1][0] = mfma16(a1, b0, acc[1][0]);
      acc[1][1] = mfma16(a1, b1, acc[1][1]);
    }
  }
  float* pb = part + (size_t)((nch * 4 + h) * 8 + b) * 4096;
#pragma unroll
  for (int mf = 0; mf < 2; mf++)
#pragma unroll
    for (int nf = 0; nf < 2; nf++) {
      int p = noff + nf * 16 + l15;
#pragma unroll
      for (int r = 0; r < 4; r++) {
        int o = moff + mf * 16 + 4 * uq + r;
        pb[o * 64 + p] = acc[mf][nf][r];
      }
    }
}

// ---------------- softmax over p (one wave per (h,b,o) row) ----------------
__global__ __launch_bounds__(256) void smax(const float* __restrict__ part,
                                            unsigned short* __restrict__ attn) {
  int row = blockIdx.x * 4 + (threadIdx.x >> 6);
  int lane = threadIdx.x & 63;
  int h = row >> 9, b = (row >> 6) & 7, o = row & 63;
  float s = 0.f;
#pragma unroll
  for (int nch = 0; nch < 8; nch++)
    s += part[(size_t)((nch * 4 + h) * 8 + b) * 4096 + o * 64 + lane];
  s *= 0.0625f;  // 1/sqrt(256)
  float m = s;
#pragma unroll
  for (int k = 32; k > 0; k >>= 1) m = fmaxf(m, __shfl_xor(m, k, 64));
  float e = __expf(s - m);
  float sum = e;
#pragma unroll
  for (int k = 32; k > 0; k >>= 1) sum += __shfl_xor(sum, k, 64);
  attn[(size_t)(h * 8 + b) * 4096 + o * 64 + lane] = f2h(e / sum);
}

// ---------------- out = attn @ v ----------------
__global__ __launch_bounds__(256) void outk(const unsigned short* __restrict__ attn,
                                            const unsigned short* __restrict__ vT,
                                            float* __restrict__ out) {
  __shared__ __align__(16) unsigned short As[64 * 64];
  __shared__ __align__(16) unsigned short Bs[256 * 64];
  int n0 = blockIdx.x * 256, b = blockIdx.y, h = blockIdx.z;
  int tid = threadIdx.x, lane = tid & 63, w = tid >> 6;
  int l15 = lane & 15, uq = lane >> 4;
  const unsigned short* ab = attn + (size_t)(h * 8 + b) * 4096;
  const unsigned short* vb = vT + (size_t)(h * 8 + b) * 16384 * 64;
  for (int p = tid; p < 512; p += 256) {
    int row = p >> 3, j = p & 7;
    *(uint4*)&As[sw(row, j * 8)] = *(const uint4*)(ab + row * 64 + j * 8);
  }
  for (int p = tid; p < 2048; p += 256) {
    int px = p >> 3, j = p & 7;
    *(uint4*)&Bs[sw(px, j * 8)] = *(const uint4*)(vb + (size_t)(n0 + px) * 64 + j * 8);
  }
  __syncthreads();
  const f32x4 fz = {0.f, 0.f, 0.f, 0.f};
  f32x4 acc[4][4];
#pragma unroll
  for (int i = 0; i < 4; i++)
#pragma unroll
    for (int j = 0; j < 4; j++) acc[i][j] = fz;
#pragma unroll
  for (int kk = 0; kk < 2; kk++) {
    f16x8 bfr[4];
#pragma unroll
    for (int nf = 0; nf < 4; nf++)
      bfr[nf] = *(const f16x8*)&Bs[sw(w * 64 + nf * 16 + l15, kk * 32 + uq * 8)];
#pragma unroll
    for (int mf = 0; mf < 4; mf++) {
      f16x8 afr = *(const f16x8*)&As[sw(mf * 16 + l15, kk * 32 + uq * 8)];
#pragma unroll
      for (int nf = 0; nf < 4; nf++) acc[mf][nf] = mfma16(afr, bfr[nf], acc[mf][nf]);
    }
  }
  float* ob = out + (size_t)b * 4194304 + (size_t)(h * 64) * 16384;
#pragma unroll
  for (int mf = 0; mf < 4; mf++)
#pragma unroll
    for (int nf = 0; nf < 4; nf++) {
      int n = n0 + w * 64 + nf * 16 + l15;
#pragma unroll
      for (int r = 0; r < 4; r++) {
        int o = mf * 16 + 4 * uq + r;
        ob[(size_t)o * 16384 + n] = acc[mf][nf][r];
      }
    }
}

extern "C" void kernel_launch(void* const* d_in, const int* in_sizes, int n_in,
                              void* d_out, int out_size, void* d_ws, size_t ws_size,
                              hipStream_t stream) {
  const float* x  = (const float*)d_in[0];
  const float* Wq = (const float*)d_in[1];
  const float* bq = (const float*)d_in[2];
  const float* Wk = (const float*)d_in[3];
  const float* bk = (const float*)d_in[4];
  const float* Wv = (const float*)d_in[5];
  const float* bv = (const float*)d_in[6];
  float* out = (float*)d_out;

  char* ws = (char*)d_ws;
  unsigned short* kbuf = (unsigned short*)(ws);
  unsigned short* vT   = (unsigned short*)(ws + 67108864);
  unsigned short* attn = (unsigned short*)(ws + 134217728);
  unsigned short* Wqv  = (unsigned short*)(ws + 134479872);
  unsigned short* Wkb  = (unsigned short*)(ws + 134742016);
  // d_out doubles as scratch: xT in first half, q in second; part reuses dead xT.
  unsigned short* xT = (unsigned short*)d_out;
  unsigned short* qb = (unsigned short*)d_out + 33554432;
  float* part = (float*)d_out;

  prep<<<dim3(2816), dim3(256), 0, stream>>>(Wq, Wv, Wk, Wqv, Wkb);
  xpose<<<dim3(256, 4, 8), dim3(256), 0, stream>>>(x, xT);
  proj<<<dim3(64, 8, 8), dim3(256), 0, stream>>>(xT, Wqv, bq, bv, qb, vT);
  convk<<<dim3(128, 8, 4), dim3(256), 0, stream>>>(xT, Wkb, bk, kbuf);
  scoresk<<<dim3(8, 8, 4), dim3(256), 0, stream>>>(qb, kbuf, part);
  smax<<<dim3(512), dim3(256), 0, stream>>>(part, attn);
  outk<<<dim3(64, 8, 4), dim3(256), 0, stream>>>(attn, vT, out);
}

// Round 3
// 528.660 us; speedup vs baseline: 1.2300x; 1.2300x over previous
//
#include <hip/hip_runtime.h>
#include <hip/hip_bf16.h>

// Channel attention (4 heads, dilated 3x3 key convs d=1,2,4,8), f16 MFMA pipeline.
// R3: convk rebuilt on mfma_f32_32x32x16_f16, 4-row blocks, weights direct from L2,
// slot-major conflict-free halo LDS, 16 barriers/block (was ~80).
//
// ws layout (bytes):
//   kbuf : [0,           67108864)   k  f16 [h][b][p][n]
//   vT   : [67108864,   134217728)   v  f16 [h][b][n][p]   (pixel-major)
//   attn : [134217728,  134479872)   attn f16 [h][b][o][p]
//   Wqv  : [134479872,  134742016)   f16 (512x256)
//   Wkb  : [134742016,  135921664)   f16 [h][t][ks32][p64][8]  (MFMA A-frag native)
// d_out reused as scratch (dead before final kernel):
//   xT   : bytes [0, 64Mi)   f16 [b][n][c]
//   q    : bytes [64Mi,128Mi) f16 [h][b][o][n]
//   part : bytes [0, 4Mi)    fp32 partial scores (written AFTER conv, xT dead)

typedef __attribute__((ext_vector_type(8))) _Float16 f16x8;
typedef __attribute__((ext_vector_type(4))) float f32x4;
typedef __attribute__((ext_vector_type(16))) float f32x16;

__device__ __forceinline__ unsigned short f2h(float f) {
  union { _Float16 h; unsigned short u; } v;
  v.h = (_Float16)f;
  return v.u;
}

__device__ __forceinline__ f32x4 mfma16(f16x8 a, f16x8 b, f32x4 c) {
  return __builtin_amdgcn_mfma_f32_16x16x32_f16(a, b, c, 0, 0, 0);
}
__device__ __forceinline__ f32x16 mfma32(f16x8 a, f16x8 b, f32x16 c) {
  return __builtin_amdgcn_mfma_f32_32x32x16_f16(a, b, c, 0, 0, 0);
}

// swizzled index into a [R][64]-ushort tile (128B rows): XOR bits 4..6 of byte off
__device__ __forceinline__ int sw(int row, int c) {
  return row * 64 + ((((c << 1) ^ ((row & 7) << 4)) >> 1));
}

// ---------------- weight prep ----------------
__global__ __launch_bounds__(256) void prep(const float* __restrict__ Wq,
                                            const float* __restrict__ Wv,
                                            const float* __restrict__ Wk,
                                            unsigned short* __restrict__ Wqv,
                                            unsigned short* __restrict__ Wkb) {
  int i = blockIdx.x * 256 + threadIdx.x;
  const int total = 131072 + 589824;
  if (i >= total) return;
  if (i < 131072) {
    Wqv[i] = f2h(i < 65536 ? Wq[i] : Wv[i - 65536]);
  } else {
    int j = i - 131072;  // (((h*9+t)*32 + ks)*64 + p)*8 + jj
    int jj = j & 7;
    int p = (j >> 3) & 63;
    int ks = (j >> 9) & 31;
    int ht = j >> 14;
    int t = ht % 9;
    int h = ht / 9;
    Wkb[j] = f2h(Wk[(size_t)((h * 64 + p) * 256 + ks * 8 + jj) * 9 + t]);
  }
}

// ---------------- x (b,c,n) fp32 -> xT (b,n,c) f16 ----------------
__global__ __launch_bounds__(256) void xpose(const float* __restrict__ x,
                                             unsigned short* __restrict__ xT) {
  __shared__ unsigned short tile[64][66];
  int n0 = blockIdx.x * 64, c0 = blockIdx.y * 64, b = blockIdx.z;
  int t = threadIdx.x;
  int r = t >> 2, q = t & 3;
  const float* src = x + (size_t)b * 4194304 + (size_t)(c0 + r) * 16384 + n0 + q * 16;
#pragma unroll
  for (int i = 0; i < 4; i++) {
    float4 v = *(const float4*)(src + i * 4);
    tile[r][q * 16 + i * 4 + 0] = f2h(v.x);
    tile[r][q * 16 + i * 4 + 1] = f2h(v.y);
    tile[r][q * 16 + i * 4 + 2] = f2h(v.z);
    tile[r][q * 16 + i * 4 + 3] = f2h(v.w);
  }
  __syncthreads();
  int c = t & 63, pq = t >> 6;
  unsigned short* dst = xT + (size_t)b * 4194304 + (size_t)n0 * 256 + c0 + c;
#pragma unroll
  for (int i = 0; i < 16; i++) {
    int px = i * 4 + pq;
    dst[(size_t)px * 256] = tile[c][px];
  }
}

// ---------------- Q/V projection: C(64x256) = Wqv-tile @ xT-tile ----------------
__global__ __launch_bounds__(256) void proj(const unsigned short* __restrict__ xT,
                                            const unsigned short* __restrict__ Wqv,
                                            const float* __restrict__ bq,
                                            const float* __restrict__ bv,
                                            unsigned short* __restrict__ qout,
                                            unsigned short* __restrict__ vT) {
  __shared__ __align__(16) unsigned short As[64 * 64];
  __shared__ __align__(16) unsigned short Bs[256 * 64];
  int n0 = blockIdx.x * 256, m0 = blockIdx.y * 64, b = blockIdx.z;
  int tid = threadIdx.x, lane = tid & 63, w = tid >> 6;
  int l15 = lane & 15, uq = lane >> 4;
  const f32x4 fz = {0.f, 0.f, 0.f, 0.f};
  f32x4 acc[4][4];
#pragma unroll
  for (int i = 0; i < 4; i++)
#pragma unroll
    for (int j = 0; j < 4; j++) acc[i][j] = fz;

  const unsigned short* xb = xT + (size_t)b * 4194304;
  for (int k0 = 0; k0 < 256; k0 += 64) {
    __syncthreads();
    for (int p = tid; p < 512; p += 256) {
      int row = p >> 3, j = p & 7;
      uint4 v = *(const uint4*)(Wqv + (size_t)(m0 + row) * 256 + k0 + j * 8);
      *(uint4*)&As[sw(row, j * 8)] = v;
    }
    for (int p = tid; p < 2048; p += 256) {
      int px = p >> 3, j = p & 7;
      uint4 v = *(const uint4*)(xb + (size_t)(n0 + px) * 256 + k0 + j * 8);
      *(uint4*)&Bs[sw(px, j * 8)] = v;
    }
    __syncthreads();
#pragma unroll
    for (int kk = 0; kk < 2; kk++) {
      f16x8 bfr[4];
#pragma unroll
      for (int nf = 0; nf < 4; nf++)
        bfr[nf] = *(const f16x8*)&Bs[sw(w * 64 + nf * 16 + l15, kk * 32 + uq * 8)];
#pragma unroll
      for (int mf = 0; mf < 4; mf++) {
        f16x8 afr = *(const f16x8*)&As[sw(mf * 16 + l15, kk * 32 + uq * 8)];
#pragma unroll
        for (int nf = 0; nf < 4; nf++) acc[mf][nf] = mfma16(afr, bfr[nf], acc[mf][nf]);
      }
    }
  }
  if (m0 < 256) {
    int h = m0 >> 6;
    unsigned short* qb = qout + (size_t)((h * 8 + b) * 64) * 16384;
#pragma unroll
    for (int mf = 0; mf < 4; mf++)
#pragma unroll
      for (int nf = 0; nf < 4; nf++) {
        int n = n0 + w * 64 + nf * 16 + l15;
#pragma unroll
        for (int r = 0; r < 4; r++) {
          int m = m0 + mf * 16 + 4 * uq + r;
          qb[(size_t)(m & 63) * 16384 + n] = f2h(acc[mf][nf][r] + bq[m]);
        }
      }
  } else {
    int m0v = m0 - 256, h = m0v >> 6;
    unsigned short* vb = vT + (size_t)(h * 8 + b) * 16384 * 64;
#pragma unroll
    for (int mf = 0; mf < 4; mf++) {
      int p0 = mf * 16 + 4 * uq;
#pragma unroll
      for (int nf = 0; nf < 4; nf++) {
        int n = n0 + w * 64 + nf * 16 + l15;
        unsigned short t0 = f2h(acc[mf][nf][0] + bv[m0v + p0 + 0]);
        unsigned short t1 = f2h(acc[mf][nf][1] + bv[m0v + p0 + 1]);
        unsigned short t2 = f2h(acc[mf][nf][2] + bv[m0v + p0 + 2]);
        unsigned short t3 = f2h(acc[mf][nf][3] + bv[m0v + p0 + 3]);
        uint2 pk;
        pk.x = (unsigned)t0 | ((unsigned)t1 << 16);
        pk.y = (unsigned)t2 | ((unsigned)t3 << 16);
        *(uint2*)&vb[(size_t)n * 64 + p0] = pk;
      }
    }
  }
}

// ---------------- dilated 3x3 conv (keys): 4 d-spaced output rows per block ----
// out[p][y][x] = sum_{c,ty,tx} W[p][c][ty][tx] * x[c][y+d(ty-1)][x+d(tx-1)]
// MFMA 32x32x16: A = weights (rows=out-ch), B = halo pixels (cols=x), K = channels.
__global__ __launch_bounds__(256, 2) void convk(const unsigned short* __restrict__ xT,
                                                const unsigned short* __restrict__ Wkb,
                                                const float* __restrict__ bk,
                                                unsigned short* __restrict__ kout) {
  // halo LDS, slot-major: [kslot 4][plane 6][px 144] x 16B blocks (55296 B)
  __shared__ __align__(16) unsigned short Bs[4 * 6 * 144 * 8];
  int g = blockIdx.x, b = blockIdx.y, h = blockIdx.z;
  int d = 1 << h;
  int gpd = 32 >> h;            // row-groups per congruence class s
  int s = g / gpd;
  int q0 = (g - s * gpd) * 4;   // base q; rows y = s + q*d
  int nq = 128 >> h;
  int tid = threadIdx.x, lane = tid & 63, w = tid >> 6;
  int l31 = lane & 31, hi = lane >> 5;
  const unsigned short* xb = xT + (size_t)b * 4194304;

  f32x16 acc[2][4];
#pragma unroll
  for (int i = 0; i < 2; i++)
#pragma unroll
    for (int j = 0; j < 4; j++)
#pragma unroll
      for (int r = 0; r < 16; r++) acc[i][j][r] = 0.f;

  // per-lane weight base: [(h*9+t)*32 + ks][p][8] with ks = c8 + kk*2 + hi, p = mo*32+l31
  const unsigned short* wl = Wkb + ((((size_t)h * 9) * 32 + hi) * 64 + l31) * 8;

  for (int c8 = 0; c8 < 32; c8 += 4) {  // channel chunk of 32 (4 k-slots of 8)
    __syncthreads();
    // stage halo: item p = (slot*6 + plane)*144 + px  (zero-padded)
    for (int p = tid; p < 3456; p += 256) {
      int px = p % 144;
      int sp = p / 144;
      int plane = sp % 6, slot = sp / 6;
      int q = q0 + plane - 1;
      int xc = px - d;
      uint4 v = {0u, 0u, 0u, 0u};
      if (q >= 0 && q < nq && xc >= 0 && xc < 128) {
        int y = s + q * d;
        v = *(const uint4*)(xb + (size_t)(y * 128 + xc) * 256 + (c8 + slot) * 8);
      }
      *(uint4*)&Bs[(size_t)p * 8] = v;
    }
    __syncthreads();
    const unsigned short* wc = wl + (size_t)c8 * 64 * 8;
#pragma unroll
    for (int t = 0; t < 9; t++) {
      int ty = t / 3, tx = t - ty * 3;
      f16x8 afr[2][2];  // [kk][mo]
#pragma unroll
      for (int kk = 0; kk < 2; kk++)
#pragma unroll
        for (int mo = 0; mo < 2; mo++)
          afr[kk][mo] = *(const f16x8*)(wc + t * 16384 + kk * 1024 + mo * 256);
      int plane = w + ty;
#pragma unroll
      for (int no = 0; no < 4; no++) {
        int u = no * 32 + d * tx + l31;
#pragma unroll
        for (int kk = 0; kk < 2; kk++) {
          int slot = kk * 2 + hi;
          f16x8 bfr = *(const f16x8*)&Bs[((slot * 6 + plane) * 144 + u) * 8];
          acc[0][no] = mfma32(afr[kk][0], bfr, acc[0][no]);
          acc[1][no] = mfma32(afr[kk][1], bfr, acc[1][no]);
        }
      }
    }
  }
  // epilogue: wave w owns output row y = s + (q0+w)*d
  int y = s + (q0 + w) * d;
  unsigned short* kb = kout + (size_t)((h * 8 + b) * 64) * 16384;
#pragma unroll
  for (int mo = 0; mo < 2; mo++)
#pragma unroll
    for (int no = 0; no < 4; no++)
#pragma unroll
      for (int r = 0; r < 16; r++) {
        int p = mo * 32 + (r & 3) + 8 * (r >> 2) + 4 * hi;
        int x = no * 32 + l31;
        kb[(size_t)p * 16384 + y * 128 + x] = f2h(acc[mo][no][r] + bk[h * 64 + p]);
      }
}

// ---------------- scores partials: q . k^T over n-chunk of 2048 ----------------
__global__ __launch_bounds__(256) void scoresk(const unsigned short* __restrict__ qin,
                                               const unsigned short* __restrict__ kin,
                                               float* __restrict__ part) {
  __shared__ __align__(16) unsigned short As[64 * 64];
  __shared__ __align__(16) unsigned short Bs[64 * 64];
  int nch = blockIdx.x, b = blockIdx.y, h = blockIdx.z;
  int tid = threadIdx.x, lane = tid & 63, w = tid >> 6;
  int l15 = lane & 15, uq = lane >> 4;
  const unsigned short* qb = qin + (size_t)((h * 8 + b) * 64) * 16384;
  const unsigned short* kb = kin + (size_t)((h * 8 + b) * 64) * 16384;
  int moff = (w >> 1) * 32, noff = (w & 1) * 32;
  const f32x4 fz = {0.f, 0.f, 0.f, 0.f};
  f32x4 acc[2][2] = {{fz, fz}, {fz, fz}};
  for (int ci = 0; ci < 32; ci++) {
    int nb = nch * 2048 + ci * 64;
    __syncthreads();
    for (int p = tid; p < 512; p += 256) {
      int row = p >> 3, j = p & 7;
      *(uint4*)&As[sw(row, j * 8)] = *(const uint4*)(qb + (size_t)row * 16384 + nb + j * 8);
      *(uint4*)&Bs[sw(row, j * 8)] = *(const uint4*)(kb + (size_t)row * 16384 + nb + j * 8);
    }
    __syncthreads();
#pragma unroll
    for (int kk = 0; kk < 2; kk++) {
      f16x8 b0 = *(const f16x8*)&Bs[sw(noff + l15, kk * 32 + uq * 8)];
      f16x8 b1 = *(const f16x8*)&Bs[sw(noff + 16 + l15, kk * 32 + uq * 8)];
      f16x8 a0 = *(const f16x8*)&As[sw(moff + l15, kk * 32 + uq * 8)];
      f16x8 a1 = *(const f16x8*)&As[sw(moff + 16 + l15, kk * 32 + uq * 8)];
      acc[0][0] = mfma16(a0, b0, acc[0][0]);
      acc[0][1] = mfma16(a0, b1, acc[0][1]);
      acc[1][0] = mfma16(a1, b0, acc[1][0]);
      acc[1][1] = mfma16(a1, b1, acc[1][1]);
    }
  }
  float* pb = part + (size_t)((nch * 4 + h) * 8 + b) * 4096;
#pragma unroll
  for (int mf = 0; mf < 2; mf++)
#pragma unroll
    for (int nf = 0; nf < 2; nf++) {
      int p = noff + nf * 16 + l15;
#pragma unroll
      for (int r = 0; r < 4; r++) {
        int o = moff + mf * 16 + 4 * uq + r;
        pb[o * 64 + p] = acc[mf][nf][r];
      }
    }
}

// ---------------- softmax over p (one wave per (h,b,o) row) ----------------
__global__ __launch_bounds__(256) void smax(const float* __restrict__ part,
                                            unsigned short* __restrict__ attn) {
  int row = blockIdx.x * 4 + (threadIdx.x >> 6);
  int lane = threadIdx.x & 63;
  int h = row >> 9, b = (row >> 6) & 7, o = row & 63;
  float s = 0.f;
#pragma unroll
  for (int nch = 0; nch < 8; nch++)
    s += part[(size_t)((nch * 4 + h) * 8 + b) * 4096 + o * 64 + lane];
  s *= 0.0625f;  // 1/sqrt(256)
  float m = s;
#pragma unroll
  for (int k = 32; k > 0; k >>= 1) m = fmaxf(m, __shfl_xor(m, k, 64));
  float e = __expf(s - m);
  float sum = e;
#pragma unroll
  for (int k = 32; k > 0; k >>= 1) sum += __shfl_xor(sum, k, 64);
  attn[(size_t)(h * 8 + b) * 4096 + o * 64 + lane] = f2h(e / sum);
}

// ---------------- out = attn @ v ----------------
__global__ __launch_bounds__(256) void outk(const unsigned short* __restrict__ attn,
                                            const unsigned short* __restrict__ vT,
                                            float* __restrict__ out) {
  __shared__ __align__(16) unsigned short As[64 * 64];
  __shared__ __align__(16) unsigned short Bs[256 * 64];
  int n0 = blockIdx.x * 256, b = blockIdx.y, h = blockIdx.z;
  int tid = threadIdx.x, lane = tid & 63, w = tid >> 6;
  int l15 = lane & 15, uq = lane >> 4;
  const unsigned short* ab = attn + (size_t)(h * 8 + b) * 4096;
  const unsigned short* vb = vT + (size_t)(h * 8 + b) * 16384 * 64;
  for (int p = tid; p < 512; p += 256) {
    int row = p >> 3, j = p & 7;
    *(uint4*)&As[sw(row, j * 8)] = *(const uint4*)(ab + row * 64 + j * 8);
  }
  for (int p = tid; p < 2048; p += 256) {
    int px = p >> 3, j = p & 7;
    *(uint4*)&Bs[sw(px, j * 8)] = *(const uint4*)(vb + (size_t)(n0 + px) * 64 + j * 8);
  }
  __syncthreads();
  const f32x4 fz = {0.f, 0.f, 0.f, 0.f};
  f32x4 acc[4][4];
#pragma unroll
  for (int i = 0; i < 4; i++)
#pragma unroll
    for (int j = 0; j < 4; j++) acc[i][j] = fz;
#pragma unroll
  for (int kk = 0; kk < 2; kk++) {
    f16x8 bfr[4];
#pragma unroll
    for (int nf = 0; nf < 4; nf++)
      bfr[nf] = *(const f16x8*)&Bs[sw(w * 64 + nf * 16 + l15, kk * 32 + uq * 8)];
#pragma unroll
    for (int mf = 0; mf < 4; mf++) {
      f16x8 afr = *(const f16x8*)&As[sw(mf * 16 + l15, kk * 32 + uq * 8)];
#pragma unroll
      for (int nf = 0; nf < 4; nf++) acc[mf][nf] = mfma16(afr, bfr[nf], acc[mf][nf]);
    }
  }
  float* ob = out + (size_t)b * 4194304 + (size_t)(h * 64) * 16384;
#pragma unroll
  for (int mf = 0; mf < 4; mf++)
#pragma unroll
    for (int nf = 0; nf < 4; nf++) {
      int n = n0 + w * 64 + nf * 16 + l15;
#pragma unroll
      for (int r = 0; r < 4; r++) {
        int o = mf * 16 + 4 * uq + r;
        ob[(size_t)o * 16384 + n] = acc[mf][nf][r];
      }
    }
}

extern "C" void kernel_launch(void* const* d_in, const int* in_sizes, int n_in,
                              void* d_out, int out_size, void* d_ws, size_t ws_size,
                              hipStream_t stream) {
  const float* x  = (const float*)d_in[0];
  const float* Wq = (const float*)d_in[1];
  const float* bq = (const float*)d_in[2];
  const float* Wk = (const float*)d_in[3];
  const float* bk = (const float*)d_in[4];
  const float* Wv = (const float*)d_in[5];
  const float* bv = (const float*)d_in[6];
  float* out = (float*)d_out;

  char* ws = (char*)d_ws;
  unsigned short* kbuf = (unsigned short*)(ws);
  unsigned short* vT   = (unsigned short*)(ws + 67108864);
  unsigned short* attn = (unsigned short*)(ws + 134217728);
  unsigned short* Wqv  = (unsigned short*)(ws + 134479872);
  unsigned short* Wkb  = (unsigned short*)(ws + 134742016);
  // d_out doubles as scratch: xT in first half, q in second; part reuses dead xT.
  unsigned short* xT = (unsigned short*)d_out;
  unsigned short* qb = (unsigned short*)d_out + 33554432;
  float* part = (float*)d_out;

  prep<<<dim3(2816), dim3(256), 0, stream>>>(Wq, Wv, Wk, Wqv, Wkb);
  xpose<<<dim3(256, 4, 8), dim3(256), 0, stream>>>(x, xT);
  proj<<<dim3(64, 8, 8), dim3(256), 0, stream>>>(xT, Wqv, bq, bv, qb, vT);
  convk<<<dim3(32, 8, 4), dim3(256), 0, stream>>>(xT, Wkb, bk, kbuf);
  scoresk<<<dim3(8, 8, 4), dim3(256), 0, stream>>>(qb, kbuf, part);
  smax<<<dim3(512), dim3(256), 0, stream>>>(part, attn);
  outk<<<dim3(64, 8, 4), dim3(256), 0, stream>>>(attn, vT, out);
}

// Round 4
// 444.688 us; speedup vs baseline: 1.4623x; 1.1888x over previous
//
#include <hip/hip_runtime.h>
#include <hip/hip_bf16.h>

// Channel attention (4 heads, dilated 3x3 key convs d=1,2,4,8), f16 MFMA pipeline.
// R4: convk gets global_load_lds(16B) staging + 2-phase double-buffered pipeline
// (16-ch chunks) + bijective XCD swizzle. Everything else unchanged from R3.
//
// ws layout (bytes):
//   kbuf : [0,           67108864)   k  f16 [h][b][p][n]
//   vT   : [67108864,   134217728)   v  f16 [h][b][n][p]   (pixel-major)
//   attn : [134217728,  134479872)   attn f16 [h][b][o][p]
//   Wqv  : [134479872,  134742016)   f16 (512x256)
//   Wkb  : [134742016,  135921664)   f16 [h][t][ks32][p64][8]  (MFMA A-frag native)
// d_out reused as scratch (dead before final kernel):
//   xT   : bytes [0, 64Mi)   f16 [b][n][c]
//   q    : bytes [64Mi,128Mi) f16 [h][b][o][n]
//   part : bytes [0, 4Mi)    fp32 partial scores (written AFTER conv, xT dead)

typedef __attribute__((ext_vector_type(8))) _Float16 f16x8;
typedef __attribute__((ext_vector_type(4))) float f32x4;
typedef __attribute__((ext_vector_type(16))) float f32x16;

__device__ __forceinline__ unsigned short f2h(float f) {
  union { _Float16 h; unsigned short u; } v;
  v.h = (_Float16)f;
  return v.u;
}

__device__ __forceinline__ f32x4 mfma16(f16x8 a, f16x8 b, f32x4 c) {
  return __builtin_amdgcn_mfma_f32_16x16x32_f16(a, b, c, 0, 0, 0);
}
__device__ __forceinline__ f32x16 mfma32(f16x8 a, f16x8 b, f32x16 c) {
  return __builtin_amdgcn_mfma_f32_32x32x16_f16(a, b, c, 0, 0, 0);
}

// swizzled index into a [R][64]-ushort tile (128B rows): XOR bits 4..6 of byte off
__device__ __forceinline__ int sw(int row, int c) {
  return row * 64 + ((((c << 1) ^ ((row & 7) << 4)) >> 1));
}

// ---------------- weight prep ----------------
__global__ __launch_bounds__(256) void prep(const float* __restrict__ Wq,
                                            const float* __restrict__ Wv,
                                            const float* __restrict__ Wk,
                                            unsigned short* __restrict__ Wqv,
                                            unsigned short* __restrict__ Wkb) {
  int i = blockIdx.x * 256 + threadIdx.x;
  const int total = 131072 + 589824;
  if (i >= total) return;
  if (i < 131072) {
    Wqv[i] = f2h(i < 65536 ? Wq[i] : Wv[i - 65536]);
  } else {
    int j = i - 131072;  // (((h*9+t)*32 + ks)*64 + p)*8 + jj
    int jj = j & 7;
    int p = (j >> 3) & 63;
    int ks = (j >> 9) & 31;
    int ht = j >> 14;
    int t = ht % 9;
    int h = ht / 9;
    Wkb[j] = f2h(Wk[(size_t)((h * 64 + p) * 256 + ks * 8 + jj) * 9 + t]);
  }
}

// ---------------- x (b,c,n) fp32 -> xT (b,n,c) f16 ----------------
__global__ __launch_bounds__(256) void xpose(const float* __restrict__ x,
                                             unsigned short* __restrict__ xT) {
  __shared__ unsigned short tile[64][66];
  int n0 = blockIdx.x * 64, c0 = blockIdx.y * 64, b = blockIdx.z;
  int t = threadIdx.x;
  int r = t >> 2, q = t & 3;
  const float* src = x + (size_t)b * 4194304 + (size_t)(c0 + r) * 16384 + n0 + q * 16;
#pragma unroll
  for (int i = 0; i < 4; i++) {
    float4 v = *(const float4*)(src + i * 4);
    tile[r][q * 16 + i * 4 + 0] = f2h(v.x);
    tile[r][q * 16 + i * 4 + 1] = f2h(v.y);
    tile[r][q * 16 + i * 4 + 2] = f2h(v.z);
    tile[r][q * 16 + i * 4 + 3] = f2h(v.w);
  }
  __syncthreads();
  int c = t & 63, pq = t >> 6;
  unsigned short* dst = xT + (size_t)b * 4194304 + (size_t)n0 * 256 + c0 + c;
#pragma unroll
  for (int i = 0; i < 16; i++) {
    int px = i * 4 + pq;
    dst[(size_t)px * 256] = tile[c][px];
  }
}

// ---------------- Q/V projection: C(64x256) = Wqv-tile @ xT-tile ----------------
__global__ __launch_bounds__(256) void proj(const unsigned short* __restrict__ xT,
                                            const unsigned short* __restrict__ Wqv,
                                            const float* __restrict__ bq,
                                            const float* __restrict__ bv,
                                            unsigned short* __restrict__ qout,
                                            unsigned short* __restrict__ vT) {
  __shared__ __align__(16) unsigned short As[64 * 64];
  __shared__ __align__(16) unsigned short Bs[256 * 64];
  int n0 = blockIdx.x * 256, m0 = blockIdx.y * 64, b = blockIdx.z;
  int tid = threadIdx.x, lane = tid & 63, w = tid >> 6;
  int l15 = lane & 15, uq = lane >> 4;
  const f32x4 fz = {0.f, 0.f, 0.f, 0.f};
  f32x4 acc[4][4];
#pragma unroll
  for (int i = 0; i < 4; i++)
#pragma unroll
    for (int j = 0; j < 4; j++) acc[i][j] = fz;

  const unsigned short* xb = xT + (size_t)b * 4194304;
  for (int k0 = 0; k0 < 256; k0 += 64) {
    __syncthreads();
    for (int p = tid; p < 512; p += 256) {
      int row = p >> 3, j = p & 7;
      uint4 v = *(const uint4*)(Wqv + (size_t)(m0 + row) * 256 + k0 + j * 8);
      *(uint4*)&As[sw(row, j * 8)] = v;
    }
    for (int p = tid; p < 2048; p += 256) {
      int px = p >> 3, j = p & 7;
      uint4 v = *(const uint4*)(xb + (size_t)(n0 + px) * 256 + k0 + j * 8);
      *(uint4*)&Bs[sw(px, j * 8)] = v;
    }
    __syncthreads();
#pragma unroll
    for (int kk = 0; kk < 2; kk++) {
      f16x8 bfr[4];
#pragma unroll
      for (int nf = 0; nf < 4; nf++)
        bfr[nf] = *(const f16x8*)&Bs[sw(w * 64 + nf * 16 + l15, kk * 32 + uq * 8)];
#pragma unroll
      for (int mf = 0; mf < 4; mf++) {
        f16x8 afr = *(const f16x8*)&As[sw(mf * 16 + l15, kk * 32 + uq * 8)];
#pragma unroll
        for (int nf = 0; nf < 4; nf++) acc[mf][nf] = mfma16(afr, bfr[nf], acc[mf][nf]);
      }
    }
  }
  if (m0 < 256) {
    int h = m0 >> 6;
    unsigned short* qb = qout + (size_t)((h * 8 + b) * 64) * 16384;
#pragma unroll
    for (int mf = 0; mf < 4; mf++)
#pragma unroll
      for (int nf = 0; nf < 4; nf++) {
        int n = n0 + w * 64 + nf * 16 + l15;
#pragma unroll
        for (int r = 0; r < 4; r++) {
          int m = m0 + mf * 16 + 4 * uq + r;
          qb[(size_t)(m & 63) * 16384 + n] = f2h(acc[mf][nf][r] + bq[m]);
        }
      }
  } else {
    int m0v = m0 - 256, h = m0v >> 6;
    unsigned short* vb = vT + (size_t)(h * 8 + b) * 16384 * 64;
#pragma unroll
    for (int mf = 0; mf < 4; mf++) {
      int p0 = mf * 16 + 4 * uq;
#pragma unroll
      for (int nf = 0; nf < 4; nf++) {
        int n = n0 + w * 64 + nf * 16 + l15;
        unsigned short t0 = f2h(acc[mf][nf][0] + bv[m0v + p0 + 0]);
        unsigned short t1 = f2h(acc[mf][nf][1] + bv[m0v + p0 + 1]);
        unsigned short t2 = f2h(acc[mf][nf][2] + bv[m0v + p0 + 2]);
        unsigned short t3 = f2h(acc[mf][nf][3] + bv[m0v + p0 + 3]);
        uint2 pk;
        pk.x = (unsigned)t0 | ((unsigned)t1 << 16);
        pk.y = (unsigned)t2 | ((unsigned)t3 << 16);
        *(uint2*)&vb[(size_t)n * 64 + p0] = pk;
      }
    }
  }
}

// ---------------- dilated 3x3 conv (keys): 4 d-spaced output rows per block ----
// 2-phase double-buffered: STAGE(c+1) via global_load_lds overlaps COMPUTE(c).
// Chunk = 16 channels (2 k-slots of 8). LDS buf: [2 slots][6 planes][144 px][16B].
__global__ __launch_bounds__(256, 2) void convk(const unsigned short* __restrict__ xT,
                                                const unsigned short* __restrict__ Wkb,
                                                const float* __restrict__ bk,
                                                unsigned short* __restrict__ kout) {
  __shared__ __align__(16) unsigned short Bs[2][2 * 6 * 144 * 8];  // 55296 B
  // bijective XCD swizzle: 1024 blocks, dispatch slot s runs orig (s%8)*128+s/8
  int orig = (blockIdx.x & 7) * 128 + (blockIdx.x >> 3);
  int g = orig & 31, b = (orig >> 5) & 7, h = orig >> 8;
  int d = 1 << h;
  int gpd = 32 >> h;            // row-groups per congruence class s
  int s = g / gpd;
  int q0 = (g - s * gpd) * 4;   // base q; rows y = s + q*d
  int nq = 128 >> h;
  int tid = threadIdx.x, lane = tid & 63, w = tid >> 6;
  int l31 = lane & 31, hi = lane >> 5;
  const unsigned short* xb = xT + (size_t)b * 4194304;

  f32x16 acc[2][4];
#pragma unroll
  for (int i = 0; i < 2; i++)
#pragma unroll
    for (int j = 0; j < 4; j++)
#pragma unroll
      for (int r = 0; r < 16; r++) acc[i][j][r] = 0.f;

  // ---- staging: 1728 items = (slot*6+plane)*144+px, each one 16B channel-block
  auto STAGE = [&](int c, int bufi) {
#pragma unroll
    for (int it = 0; it < 7; it++) {
      int base = it * 256 + w * 64;  // wave-uniform LDS base item
      if (base < 1728) {
        int p = base + lane;
        int px = p % 144;
        int sp = p / 144;                    // 0..11
        int plane = sp % 6, slot = sp / 6;   // slot 0..1
        int q = q0 + plane - 1;
        int xc = px - d;
        if (q >= 0 && q < nq && xc >= 0 && xc < 128) {
          int y = s + q * d;
          const unsigned short* gsrc =
              xb + (size_t)(y * 128 + xc) * 256 + c * 16 + slot * 8;
          __builtin_amdgcn_global_load_lds(
              (const __attribute__((address_space(1))) void*)gsrc,
              (__attribute__((address_space(3))) void*)&Bs[bufi][base * 8], 16, 0, 0);
        } else {
          uint4 z = {0u, 0u, 0u, 0u};
          *(uint4*)&Bs[bufi][(size_t)p * 8] = z;
        }
      }
    }
  };

  STAGE(0, 0);
  __syncthreads();
  for (int c = 0; c < 16; c++) {
    int bufi = c & 1;
    if (c < 15) STAGE(c + 1, bufi ^ 1);
    // ---- compute chunk c from Bs[bufi]
#pragma unroll
    for (int t = 0; t < 9; t++) {
      int ty = t / 3, tx = t - ty * 3;
      f16x8 a0 = *(const f16x8*)(Wkb + (size_t)(((h * 9 + t) * 32 + c * 2 + hi) * 64 + l31) * 8);
      f16x8 a1 = *(const f16x8*)(Wkb + (size_t)(((h * 9 + t) * 32 + c * 2 + hi) * 64 + 32 + l31) * 8);
      int plane = w + ty;
#pragma unroll
      for (int no = 0; no < 4; no++) {
        int u = no * 32 + d * tx + l31;
        f16x8 bfr = *(const f16x8*)&Bs[bufi][((hi * 6 + plane) * 144 + u) * 8];
        acc[0][no] = mfma32(a0, bfr, acc[0][no]);
        acc[1][no] = mfma32(a1, bfr, acc[1][no]);
      }
    }
    __syncthreads();  // drains chunk c+1 loads; protects buf reuse
  }

  // epilogue: wave w owns output row y = s + (q0+w)*d
  int y = s + (q0 + w) * d;
  unsigned short* kb = kout + (size_t)((h * 8 + b) * 64) * 16384;
#pragma unroll
  for (int mo = 0; mo < 2; mo++)
#pragma unroll
    for (int no = 0; no < 4; no++)
#pragma unroll
      for (int r = 0; r < 16; r++) {
        int p = mo * 32 + (r & 3) + 8 * (r >> 2) + 4 * hi;
        int x = no * 32 + l31;
        kb[(size_t)p * 16384 + y * 128 + x] = f2h(acc[mo][no][r] + bk[h * 64 + p]);
      }
}

// ---------------- scores partials: q . k^T over n-chunk of 2048 ----------------
__global__ __launch_bounds__(256) void scoresk(const unsigned short* __restrict__ qin,
                                               const unsigned short* __restrict__ kin,
                                               float* __restrict__ part) {
  __shared__ __align__(16) unsigned short As[64 * 64];
  __shared__ __align__(16) unsigned short Bs[64 * 64];
  int nch = blockIdx.x, b = blockIdx.y, h = blockIdx.z;
  int tid = threadIdx.x, lane = tid & 63, w = tid >> 6;
  int l15 = lane & 15, uq = lane >> 4;
  const unsigned short* qb = qin + (size_t)((h * 8 + b) * 64) * 16384;
  const unsigned short* kb = kin + (size_t)((h * 8 + b) * 64) * 16384;
  int moff = (w >> 1) * 32, noff = (w & 1) * 32;
  const f32x4 fz = {0.f, 0.f, 0.f, 0.f};
  f32x4 acc[2][2] = {{fz, fz}, {fz, fz}};
  for (int ci = 0; ci < 32; ci++) {
    int nb = nch * 2048 + ci * 64;
    __syncthreads();
    for (int p = tid; p < 512; p += 256) {
      int row = p >> 3, j = p & 7;
      *(uint4*)&As[sw(row, j * 8)] = *(const uint4*)(qb + (size_t)row * 16384 + nb + j * 8);
      *(uint4*)&Bs[sw(row, j * 8)] = *(const uint4*)(kb + (size_t)row * 16384 + nb + j * 8);
    }
    __syncthreads();
#pragma unroll
    for (int kk = 0; kk < 2; kk++) {
      f16x8 b0 = *(const f16x8*)&Bs[sw(noff + l15, kk * 32 + uq * 8)];
      f16x8 b1 = *(const f16x8*)&Bs[sw(noff + 16 + l15, kk * 32 + uq * 8)];
      f16x8 a0 = *(const f16x8*)&As[sw(moff + l15, kk * 32 + uq * 8)];
      f16x8 a1 = *(const f16x8*)&As[sw(moff + 16 + l15, kk * 32 + uq * 8)];
      acc[0][0] = mfma16(a0, b0, acc[0][0]);
      acc[0][1] = mfma16(a0, b1, acc[0][1]);
      acc[1][0] = mfma16(a1, b0, acc[1][0]);
      acc[1][1] = mfma16(a1, b1, acc[1][1]);
    }
  }
  float* pb = part + (size_t)((nch * 4 + h) * 8 + b) * 4096;
#pragma unroll
  for (int mf = 0; mf < 2; mf++)
#pragma unroll
    for (int nf = 0; nf < 2; nf++) {
      int p = noff + nf * 16 + l15;
#pragma unroll
      for (int r = 0; r < 4; r++) {
        int o = moff + mf * 16 + 4 * uq + r;
        pb[o * 64 + p] = acc[mf][nf][r];
      }
    }
}

// ---------------- softmax over p (one wave per (h,b,o) row) ----------------
__global__ __launch_bounds__(256) void smax(const float* __restrict__ part,
                                            unsigned short* __restrict__ attn) {
  int row = blockIdx.x * 4 + (threadIdx.x >> 6);
  int lane = threadIdx.x & 63;
  int h = row >> 9, b = (row >> 6) & 7, o = row & 63;
  float s = 0.f;
#pragma unroll
  for (int nch = 0; nch < 8; nch++)
    s += part[(size_t)((nch * 4 + h) * 8 + b) * 4096 + o * 64 + lane];
  s *= 0.0625f;  // 1/sqrt(256)
  float m = s;
#pragma unroll
  for (int k = 32; k > 0; k >>= 1) m = fmaxf(m, __shfl_xor(m, k, 64));
  float e = __expf(s - m);
  float sum = e;
#pragma unroll
  for (int k = 32; k > 0; k >>= 1) sum += __shfl_xor(sum, k, 64);
  attn[(size_t)(h * 8 + b) * 4096 + o * 64 + lane] = f2h(e / sum);
}

// ---------------- out = attn @ v ----------------
__global__ __launch_bounds__(256) void outk(const unsigned short* __restrict__ attn,
                                            const unsigned short* __restrict__ vT,
                                            float* __restrict__ out) {
  __shared__ __align__(16) unsigned short As[64 * 64];
  __shared__ __align__(16) unsigned short Bs[256 * 64];
  int n0 = blockIdx.x * 256, b = blockIdx.y, h = blockIdx.z;
  int tid = threadIdx.x, lane = tid & 63, w = tid >> 6;
  int l15 = lane & 15, uq = lane >> 4;
  const unsigned short* ab = attn + (size_t)(h * 8 + b) * 4096;
  const unsigned short* vb = vT + (size_t)(h * 8 + b) * 16384 * 64;
  for (int p = tid; p < 512; p += 256) {
    int row = p >> 3, j = p & 7;
    *(uint4*)&As[sw(row, j * 8)] = *(const uint4*)(ab + row * 64 + j * 8);
  }
  for (int p = tid; p < 2048; p += 256) {
    int px = p >> 3, j = p & 7;
    *(uint4*)&Bs[sw(px, j * 8)] = *(const uint4*)(vb + (size_t)(n0 + px) * 64 + j * 8);
  }
  __syncthreads();
  const f32x4 fz = {0.f, 0.f, 0.f, 0.f};
  f32x4 acc[4][4];
#pragma unroll
  for (int i = 0; i < 4; i++)
#pragma unroll
    for (int j = 0; j < 4; j++) acc[i][j] = fz;
#pragma unroll
  for (int kk = 0; kk < 2; kk++) {
    f16x8 bfr[4];
#pragma unroll
    for (int nf = 0; nf < 4; nf++)
      bfr[nf] = *(const f16x8*)&Bs[sw(w * 64 + nf * 16 + l15, kk * 32 + uq * 8)];
#pragma unroll
    for (int mf = 0; mf < 4; mf++) {
      f16x8 afr = *(const f16x8*)&As[sw(mf * 16 + l15, kk * 32 + uq * 8)];
#pragma unroll
      for (int nf = 0; nf < 4; nf++) acc[mf][nf] = mfma16(afr, bfr[nf], acc[mf][nf]);
    }
  }
  float* ob = out + (size_t)b * 4194304 + (size_t)(h * 64) * 16384;
#pragma unroll
  for (int mf = 0; mf < 4; mf++)
#pragma unroll
    for (int nf = 0; nf < 4; nf++) {
      int n = n0 + w * 64 + nf * 16 + l15;
#pragma unroll
      for (int r = 0; r < 4; r++) {
        int o = mf * 16 + 4 * uq + r;
        ob[(size_t)o * 16384 + n] = acc[mf][nf][r];
      }
    }
}

extern "C" void kernel_launch(void* const* d_in, const int* in_sizes, int n_in,
                              void* d_out, int out_size, void* d_ws, size_t ws_size,
                              hipStream_t stream) {
  const float* x  = (const float*)d_in[0];
  const float* Wq = (const float*)d_in[1];
  const float* bq = (const float*)d_in[2];
  const float* Wk = (const float*)d_in[3];
  const float* bk = (const float*)d_in[4];
  const float* Wv = (const float*)d_in[5];
  const float* bv = (const float*)d_in[6];
  float* out = (float*)d_out;

  char* ws = (char*)d_ws;
  unsigned short* kbuf = (unsigned short*)(ws);
  unsigned short* vT   = (unsigned short*)(ws + 67108864);
  unsigned short* attn = (unsigned short*)(ws + 134217728);
  unsigned short* Wqv  = (unsigned short*)(ws + 134479872);
  unsigned short* Wkb  = (unsigned short*)(ws + 134742016);
  // d_out doubles as scratch: xT in first half, q in second; part reuses dead xT.
  unsigned short* xT = (unsigned short*)d_out;
  unsigned short* qb = (unsigned short*)d_out + 33554432;
  float* part = (float*)d_out;

  prep<<<dim3(2816), dim3(256), 0, stream>>>(Wq, Wv, Wk, Wqv, Wkb);
  xpose<<<dim3(256, 4, 8), dim3(256), 0, stream>>>(x, xT);
  proj<<<dim3(64, 8, 8), dim3(256), 0, stream>>>(xT, Wqv, bq, bv, qb, vT);
  convk<<<dim3(1024), dim3(256), 0, stream>>>(xT, Wkb, bk, kbuf);
  scoresk<<<dim3(8, 8, 4), dim3(256), 0, stream>>>(qb, kbuf, part);
  smax<<<dim3(512), dim3(256), 0, stream>>>(part, attn);
  outk<<<dim3(64, 8, 4), dim3(256), 0, stream>>>(attn, vT, out);
}